// Round 8
// baseline (222.156 us; speedup 1.0000x reference)
//
#include <hip/hip_runtime.h>
#include <math.h>

typedef __attribute__((ext_vector_type(8))) short bf16x8;
typedef __attribute__((ext_vector_type(4))) short bf16x4;
typedef __attribute__((ext_vector_type(4))) float f32x4;

#define MFMA16(a, b, c) __builtin_amdgcn_mfma_f32_16x16x32_bf16(a, b, c, 0, 0, 0)

#define WPL (1024u * 1024u)       // W plane, ushorts (2 MB)
#define XPL (4u * 1024u * 1024u)  // X/head plane, ushorts (8 MB)

// round-to-nearest-even fp32 -> bf16
__device__ __forceinline__ unsigned short rne_bf16(float f) {
    unsigned u = __float_as_uint(f);
    u += 0x7FFFu + ((u >> 16) & 1u);
    return (unsigned short)(u >> 16);
}

// async global->LDS, 16B per lane. LDS dest = wave-uniform base + lane*16.
typedef const __attribute__((address_space(1))) unsigned int* gas_t;
typedef __attribute__((address_space(3))) unsigned int* las_t;
__device__ __forceinline__ void glds16(const void* g, void* l) {
    __builtin_amdgcn_global_load_lds((gas_t)g, (las_t)l, 16, 0, 0);
}

// ---------------------------------------------------------------------------
// Converter: Wq/Wk/Wv/Wo -> rne bf16 planes; query/key/value -> rne planes.
// All row-major. blocks 0..4095 = W, 4096..16383 = X.
// ---------------------------------------------------------------------------
__global__ __launch_bounds__(256)
void convert_all(const float* __restrict__ Wq, const float* __restrict__ Wk,
                 const float* __restrict__ Wv, const float* __restrict__ Wo,
                 const float* __restrict__ Xq, const float* __restrict__ Xk,
                 const float* __restrict__ Xv,
                 unsigned short* __restrict__ Wb, unsigned short* __restrict__ Xb) {
    int blk = blockIdx.x;
    const float* S;
    unsigned short* D;
    if (blk < 4096) {
        int which = blk >> 10;
        S = which == 0 ? Wq : which == 1 ? Wk : which == 2 ? Wv : Wo;
        D = Wb + (size_t)which * WPL;
        blk &= 1023;
    } else {
        blk -= 4096;
        int which = blk >> 12;
        S = which == 0 ? Xq : which == 1 ? Xk : Xv;
        D = Xb + (size_t)which * XPL;
        blk &= 4095;
    }
    int i = (blk * 256 + threadIdx.x) * 4;
    float4 f = *(const float4*)&S[i];
    bf16x4 h;
    h[0] = (short)rne_bf16(f.x);
    h[1] = (short)rne_bf16(f.y);
    h[2] = (short)rne_bf16(f.z);
    h[3] = (short)rne_bf16(f.w);
    *(bf16x4*)&D[i] = h;
}

// ---------------------------------------------------------------------------
// Universal single-pass GEMM with 2-stage LDS double buffer.
// C[m][n] = sum_k A[m][k]*B[n][k], M=4096, N=K=1024, bf16 row-major A/B.
// 128x128 tile, BK=64, 4 waves (2x2 of 64x64, 4x4 acc). Pipeline:
//   stage(buf0,kt0); barrier; loop { stage(buf^1,kt+1); mfma(buf,kt);
//   barrier (vmcnt(0) drain lands ~620cy after issue -> latency hidden) }
// Additive bank swizzle: LDS slot s of row r holds global chunk (s+2r)&7.
// mode (modeBase+z): 0 Q->[b][h][s][dh]; 1 K->frag-tiled per head;
//                    2 V->frag-tiled transposed per head; 3 fp32 C row-major.
// ---------------------------------------------------------------------------
__global__ __launch_bounds__(256)
void gemm_ab(const unsigned short* __restrict__ Abase,
             const unsigned short* __restrict__ Bbase,
             unsigned short* __restrict__ QKV, float* __restrict__ Cf,
             int modeBase) {
    __shared__ unsigned short AS[2][128 * 64], BS[2][128 * 64];
    const int z = blockIdx.z, mode = modeBase + z;
    const unsigned short* A = Abase + (size_t)z * XPL;
    const unsigned short* B = Bbase + (size_t)z * WPL;

    const int t = threadIdx.x, lane = t & 63, w = t >> 6;
    const int quad = lane >> 4, l15 = lane & 15;
    const int wr = w & 1, wc = w >> 1;
    const int rowBase = blockIdx.y * 128, colBase = blockIdx.x * 128;

    // staging: instr e covers rows [e*32 + w*8, +8); lane -> (row: lane>>3,
    // slot: lane&7); global chunk cg = (slot + 2*row)&7 (coalesced per row).
    const int srow = lane >> 3;
    const int cg = ((lane & 7) + 2 * srow) & 7;
    const unsigned short *gA[4], *gB[4];
    int lOff[4];
    #pragma unroll
    for (int e = 0; e < 4; e++) {
        int row = e * 32 + w * 8 + srow;
        gA[e] = A + (size_t)(rowBase + row) * 1024 + cg * 8;
        gB[e] = B + (size_t)(colBase + row) * 1024 + cg * 8;
        lOff[e] = (e * 32 + w * 8) * 64;
    }

    // fragment addresses: row ra needs chunk kk*4+quad at slot (kk*4+quad-2*ra)&7
    const int s0 = (quad - 2 * l15) & 7;
    const int c0 = s0 * 8, c1 = ((s0 + 4) & 7) * 8;
    int aOff[4], bOff[4];
    #pragma unroll
    for (int i = 0; i < 4; i++) {
        aOff[i] = (wr * 64 + i * 16 + l15) * 64;
        bOff[i] = (wc * 64 + i * 16 + l15) * 64;
    }

    f32x4 acc[4][4] = {};

    // prologue: stage kt=0 into buf 0
    #pragma unroll
    for (int e = 0; e < 4; e++) {
        glds16(gA[e], &AS[0][lOff[e]]);
        glds16(gB[e], &BS[0][lOff[e]]);
    }
    __syncthreads();

    for (int kt = 0; kt < 16; kt++) {
        const int buf = kt & 1;
        if (kt + 1 < 16) {  // issue next tile's loads into the other buffer
            const int ko = (kt + 1) * 64, nb = buf ^ 1;
            #pragma unroll
            for (int e = 0; e < 4; e++) {
                glds16(gA[e] + ko, &AS[nb][lOff[e]]);
                glds16(gB[e] + ko, &BS[nb][lOff[e]]);
            }
        }

        bf16x8 af[4], bfr[4];
        #pragma unroll
        for (int i = 0; i < 4; i++) af[i] = *(const bf16x8*)&AS[buf][aOff[i] + c0];
        #pragma unroll
        for (int j = 0; j < 4; j++) bfr[j] = *(const bf16x8*)&BS[buf][bOff[j] + c0];
        #pragma unroll
        for (int j = 0; j < 4; j++)
            #pragma unroll
            for (int i = 0; i < 4; i++)
                acc[i][j] = MFMA16(af[i], bfr[j], acc[i][j]);

        #pragma unroll
        for (int i = 0; i < 4; i++) af[i] = *(const bf16x8*)&AS[buf][aOff[i] + c1];
        #pragma unroll
        for (int j = 0; j < 4; j++) bfr[j] = *(const bf16x8*)&BS[buf][bOff[j] + c1];
        #pragma unroll
        for (int j = 0; j < 4; j++)
            #pragma unroll
            for (int i = 0; i < 4; i++)
                acc[i][j] = MFMA16(af[i], bfr[j], acc[i][j]);

        __syncthreads();  // drains vmcnt(0): next buf ready; this buf free
    }

    // epilogue (C/D: col = lane&15, row = quad*4 + r)
    if (mode == 3) {
        #pragma unroll
        for (int i = 0; i < 4; i++)
            #pragma unroll
            for (int j = 0; j < 4; j++)
                #pragma unroll
                for (int r = 0; r < 4; r++) {
                    int m = rowBase + wr * 64 + i * 16 + quad * 4 + r;
                    int n = colBase + wc * 64 + j * 16 + l15;
                    Cf[(size_t)m * 1024 + n] = acc[i][j][r];
                }
    } else {
        unsigned short* O = QKV + (size_t)z * XPL;
        #pragma unroll
        for (int i = 0; i < 4; i++)
            #pragma unroll
            for (int j = 0; j < 4; j++)
                #pragma unroll
                for (int r = 0; r < 4; r++) {
                    int m = rowBase + wr * 64 + i * 16 + quad * 4 + r;
                    int n = colBase + wc * 64 + j * 16 + l15;
                    int bb = m >> 10, s = m & 1023, hh = n >> 6, dh = n & 63;
                    size_t hb = ((size_t)(bb * 16 + hh)) << 16;
                    unsigned short v = rne_bf16(acc[i][j][r]);
                    if (mode == 0) {
                        O[hb + s * 64 + dh] = v;             // Q row-major/head
                    } else if (mode == 1) {                  // K B-frag tiled
                        O[hb + (size_t)((s >> 4) * 2 + (dh >> 5)) * 512 +
                          ((dh >> 3) & 3) * 128 + (s & 15) * 8 + (dh & 7)] = v;
                    } else {                                 // V^T B-frag tiled
                        O[hb + (size_t)((dh >> 4) * 32 + (s >> 5)) * 512 +
                          ((s >> 3) & 3) * 128 + (dh & 15) * 8 + (s & 7)] = v;
                    }
                }
    }
}

// ---------------------------------------------------------------------------
// Flash attention, barrier-free K-loop: K/V fragments loaded straight from
// frag-tiled global planes (coalesced 1 KB per load, L2-resident). No-max
// softmax (scores bounded). Wave owns 32 q-rows; block = 128 q-rows.
// P round-trip through per-wave LDS with additive chunk swizzle.
// ---------------------------------------------------------------------------
__global__ __launch_bounds__(256)
void attn_flat(const unsigned short* __restrict__ Qp,
               const unsigned short* __restrict__ Kf,
               const unsigned short* __restrict__ Vf,
               const int* __restrict__ mask, const float* __restrict__ gamma,
               unsigned short* __restrict__ WSr) {
    __shared__ int maskS[1024];
    __shared__ unsigned short Ph[4][32 * 72];

    const int t = threadIdx.x, lane = t & 63, w = t >> 6;
    const int quad = lane >> 4, l15 = lane & 15;
    const int q0 = blockIdx.x * 128, h = blockIdx.y, b = blockIdx.z;
    const size_t hb = ((size_t)(b * 16 + h)) << 16;

    ((int4*)maskS)[t] = ((const int4*)(mask + b * 1024))[t];

    bf16x8 qf[2][2];
    #pragma unroll
    for (int mi = 0; mi < 2; mi++) {
        size_t qb = hb + (size_t)(q0 + w * 32 + mi * 16 + l15) * 64 + quad * 8;
        qf[mi][0] = *(const bf16x8*)&Qp[qb];
        qf[mi][1] = *(const bf16x8*)&Qp[qb + 32];
    }

    f32x4 o[2][4] = {};
    float lsum[2][4] = {{0.f, 0.f, 0.f, 0.f}, {0.f, 0.f, 0.f, 0.f}};
    unsigned short* P = Ph[w];

    __syncthreads();  // maskS ready (only block-wide sync in the kernel)

    for (int jt = 0; jt < 16; jt++) {
        const int j0 = jt * 64;
        if (maskS[j0]) break;  // monotonic mask
        const bool partial = maskS[j0 + 63] != 0;

        // K fragments (coalesced 1 KB each)
        bf16x8 kv[4][2];
        #pragma unroll
        for (int nj = 0; nj < 4; nj++)
            #pragma unroll
            for (int kk = 0; kk < 2; kk++)
                kv[nj][kk] = *(const bf16x8*)&Kf[hb + (size_t)((jt * 4 + nj) * 2 + kk) * 512 + lane * 8];

        f32x4 s4[2][4] = {};
        #pragma unroll
        for (int nj = 0; nj < 4; nj++)
            #pragma unroll
            for (int kk = 0; kk < 2; kk++)
                #pragma unroll
                for (int mi = 0; mi < 2; mi++)
                    s4[mi][nj] = MFMA16(qf[mi][kk], kv[nj][kk], s4[mi][nj]);

        // V fragments issued early (overlap with exp below)
        bf16x8 vv[4][2];
        #pragma unroll
        for (int dt = 0; dt < 4; dt++)
            #pragma unroll
            for (int ks = 0; ks < 2; ks++)
                vv[dt][ks] = *(const bf16x8*)&Vf[hb + (size_t)(dt * 32 + jt * 2 + ks) * 512 + lane * 8];

        // p = exp(s/8) (no max needed), write swizzled bf16 P
        #pragma unroll
        for (int mi = 0; mi < 2; mi++)
            #pragma unroll
            for (int nj = 0; nj < 4; nj++) {
                int mk = partial ? maskS[j0 + nj * 16 + l15] : 0;
                #pragma unroll
                for (int r = 0; r < 4; r++) {
                    float p = mk ? 0.f : __expf(s4[mi][nj][r] * 0.125f);
                    lsum[mi][r] += p;
                    int rowW = mi * 16 + quad * 4 + r;
                    int slot = ((nj * 2 + (l15 >> 3)) - 2 * rowW) & 7;
                    P[rowW * 72 + slot * 8 + (l15 & 7)] = rne_bf16(p);
                }
            }

        // P fragments (uniform bank groups), then O += P V
        bf16x8 pf[2][2];
        #pragma unroll
        for (int mi = 0; mi < 2; mi++) {
            int rowR = mi * 16 + l15;
            int sl0 = (quad - 2 * rowR) & 7;
            pf[mi][0] = *(const bf16x8*)&P[rowR * 72 + sl0 * 8];
            pf[mi][1] = *(const bf16x8*)&P[rowR * 72 + ((sl0 + 4) & 7) * 8];
        }
        #pragma unroll
        for (int dt = 0; dt < 4; dt++)
            #pragma unroll
            for (int ks = 0; ks < 2; ks++)
                #pragma unroll
                for (int mi = 0; mi < 2; mi++)
                    o[mi][dt] = MFMA16(pf[mi][ks], vv[dt][ks], o[mi][dt]);
    }

    #pragma unroll
    for (int mi = 0; mi < 2; mi++)
        #pragma unroll
        for (int r = 0; r < 4; r++) {
            lsum[mi][r] += __shfl_xor(lsum[mi][r], 1);
            lsum[mi][r] += __shfl_xor(lsum[mi][r], 2);
            lsum[mi][r] += __shfl_xor(lsum[mi][r], 4);
            lsum[mi][r] += __shfl_xor(lsum[mi][r], 8);
        }

    // epilogue: WS row-major [b*1024+s][h*64+dh], gamma/l fused
    const float g = gamma[h];
    #pragma unroll
    for (int mi = 0; mi < 2; mi++)
        #pragma unroll
        for (int r = 0; r < 4; r++) {
            int qrow = q0 + w * 32 + mi * 16 + quad * 4 + r;
            float sc = g / lsum[mi][r];
            size_t base = ((size_t)b * 1024 + qrow) * 1024 + h * 64;
            #pragma unroll
            for (int dt = 0; dt < 4; dt++)
                WSr[base + dt * 16 + l15] = rne_bf16(o[mi][dt][r] * sc);
        }
}

// ---------------------------------------------------------------------------
extern "C" void kernel_launch(void* const* d_in, const int* in_sizes, int n_in,
                              void* d_out, int out_size, void* d_ws, size_t ws_size,
                              hipStream_t stream) {
    const float* query = (const float*)d_in[0];
    const float* key   = (const float*)d_in[1];
    const float* value = (const float*)d_in[2];
    const int*   mask  = (const int*)d_in[3];
    const float* Wq    = (const float*)d_in[4];
    const float* Wk    = (const float*)d_in[5];
    const float* Wv    = (const float*)d_in[6];
    const float* Wo    = (const float*)d_in[7];
    const float* gamma = (const float*)d_in[8];
    float* out = (float*)d_out;

    unsigned short* u = (unsigned short*)d_ws;
    // 56 MB layout (28M ushorts):
    unsigned short* Xb  = u;            // Xq,Xk,Xv bf16 row-major (3 x XPL)
    unsigned short* QKV = u + 3 * XPL;  // Qp, Kf, Vf head planes (3 x XPL)
    unsigned short* Wb  = u + 6 * XPL;  // Wq,Wk,Wv,Wo bf16 row-major (4 x WPL)
    unsigned short* WSr = Xb;           // alias: Xq dead after proj
    unsigned short* Qp = QKV, *Kfp = QKV + XPL, *Vfp = QKV + 2 * XPL;
    unsigned short* Wob = Wb + 3 * WPL;

    convert_all<<<16384, 256, 0, stream>>>(Wq, Wk, Wv, Wo, query, key, value, Wb, Xb);

    gemm_ab<<<dim3(8, 32, 3), 256, 0, stream>>>(Xb, Wb, QKV, nullptr, 0);

    attn_flat<<<dim3(8, 16, 4), 256, 0, stream>>>(Qp, Kfp, Vfp, mask, gamma, WSr);

    gemm_ab<<<dim3(8, 32, 1), 256, 0, stream>>>(WSr, Wob, nullptr, out, 3);
}

// Round 9
// 218.976 us; speedup vs baseline: 1.0145x; 1.0145x over previous
//
#include <hip/hip_runtime.h>
#include <math.h>

typedef __attribute__((ext_vector_type(8))) short bf16x8;
typedef __attribute__((ext_vector_type(4))) short bf16x4;
typedef __attribute__((ext_vector_type(4))) float f32x4;

#define MFMA16(a, b, c) __builtin_amdgcn_mfma_f32_16x16x32_bf16(a, b, c, 0, 0, 0)

#define WPL (1024u * 1024u)       // W plane, ushorts (2 MB)
#define XPL (4u * 1024u * 1024u)  // X/head plane, ushorts (8 MB)

// round-to-nearest-even fp32 -> bf16
__device__ __forceinline__ unsigned short rne_bf16(float f) {
    unsigned u = __float_as_uint(f);
    u += 0x7FFFu + ((u >> 16) & 1u);
    return (unsigned short)(u >> 16);
}

// async global->LDS, 16B per lane. LDS dest = wave-uniform base + lane*16.
typedef const __attribute__((address_space(1))) unsigned int* gas_t;
typedef __attribute__((address_space(3))) unsigned int* las_t;
__device__ __forceinline__ void glds16(const void* g, void* l) {
    __builtin_amdgcn_global_load_lds((gas_t)g, (las_t)l, 16, 0, 0);
}

// ---------------------------------------------------------------------------
// Converter: Wq/Wk/Wv/Wo -> rne bf16 planes; query/key/value -> rne planes.
// All row-major. blocks 0..4095 = W, 4096..16383 = X.
// ---------------------------------------------------------------------------
__global__ __launch_bounds__(256)
void convert_all(const float* __restrict__ Wq, const float* __restrict__ Wk,
                 const float* __restrict__ Wv, const float* __restrict__ Wo,
                 const float* __restrict__ Xq, const float* __restrict__ Xk,
                 const float* __restrict__ Xv,
                 unsigned short* __restrict__ Wb, unsigned short* __restrict__ Xb) {
    int blk = blockIdx.x;
    const float* S;
    unsigned short* D;
    if (blk < 4096) {
        int which = blk >> 10;
        S = which == 0 ? Wq : which == 1 ? Wk : which == 2 ? Wv : Wo;
        D = Wb + (size_t)which * WPL;
        blk &= 1023;
    } else {
        blk -= 4096;
        int which = blk >> 12;
        S = which == 0 ? Xq : which == 1 ? Xk : Xv;
        D = Xb + (size_t)which * XPL;
        blk &= 4095;
    }
    int i = (blk * 256 + threadIdx.x) * 4;
    float4 f = *(const float4*)&S[i];
    bf16x4 h;
    h[0] = (short)rne_bf16(f.x);
    h[1] = (short)rne_bf16(f.y);
    h[2] = (short)rne_bf16(f.z);
    h[3] = (short)rne_bf16(f.w);
    *(bf16x4*)&D[i] = h;
}

// ---------------------------------------------------------------------------
// Q/K/V projection GEMM (r5-proven body): C[m][n] = sum_k A[m][k]*B[n][k],
// 128x128 tile, BK=32, single-buffer glds16 staging, XOR chunk swizzle
// (c ^ ((row>>1)&3); 64B row stride -> 0 measured conflicts).
// Epilogue: z=0 Q row-major/head; z=1 K frag-tiled; z=2 V^T frag-tiled.
// ---------------------------------------------------------------------------
__global__ __launch_bounds__(256)
void gemm_proj(const unsigned short* __restrict__ Xbase,
               const unsigned short* __restrict__ Wb,
               unsigned short* __restrict__ QKV) {
    __shared__ unsigned short AS[128 * 32];
    __shared__ unsigned short BS[128 * 32];

    const int z = blockIdx.z;
    const unsigned short* A = Xbase + (size_t)z * XPL;
    const unsigned short* B = Wb + (size_t)z * WPL;

    const int t = threadIdx.x, lane = t & 63, w = t >> 6;
    const int quad = lane >> 4, l15 = lane & 15;
    const int wr = w & 1, wc = w >> 1;
    const int rowBase = blockIdx.y * 128, colBase = blockIdx.x * 128;

    const unsigned short* gA[2];
    const unsigned short* gB[2];
    unsigned short* lA[2];
    unsigned short* lB[2];
    #pragma unroll
    for (int e = 0; e < 2; e++) {
        int row = w * 32 + e * 16 + (lane >> 2);
        int cg = (lane & 3) ^ ((row >> 1) & 3);
        gA[e] = A + (size_t)(rowBase + row) * 1024 + cg * 8;
        gB[e] = B + (size_t)(colBase + row) * 1024 + cg * 8;
        lA[e] = &AS[(w * 32 + e * 16) * 32];
        lB[e] = &BS[(w * 32 + e * 16) * 32];
    }

    int aAd[4], bAd[4];
    #pragma unroll
    for (int i = 0; i < 4; i++) {
        int ra = wr * 64 + i * 16 + l15;
        aAd[i] = ra * 32 + (quad ^ ((ra >> 1) & 3)) * 8;
        int rb = wc * 64 + i * 16 + l15;
        bAd[i] = rb * 32 + (quad ^ ((rb >> 1) & 3)) * 8;
    }

    f32x4 acc[4][4] = {};

    for (int kt = 0; kt < 32; kt++) {
        if (kt) __syncthreads();
        const int ko = kt * 32;
        glds16(gA[0] + ko, lA[0]);
        glds16(gA[1] + ko, lA[1]);
        glds16(gB[0] + ko, lB[0]);
        glds16(gB[1] + ko, lB[1]);
        __syncthreads();

        bf16x8 af[4], bfr[4];
        #pragma unroll
        for (int i = 0; i < 4; i++) af[i] = *(const bf16x8*)&AS[aAd[i]];
        #pragma unroll
        for (int j = 0; j < 4; j++) bfr[j] = *(const bf16x8*)&BS[bAd[j]];
        #pragma unroll
        for (int j = 0; j < 4; j++)
            #pragma unroll
            for (int i = 0; i < 4; i++)
                acc[i][j] = MFMA16(af[i], bfr[j], acc[i][j]);
    }

    unsigned short* O = QKV + (size_t)z * XPL;
    #pragma unroll
    for (int i = 0; i < 4; i++)
        #pragma unroll
        for (int j = 0; j < 4; j++)
            #pragma unroll
            for (int r = 0; r < 4; r++) {
                int m = rowBase + wr * 64 + i * 16 + quad * 4 + r;
                int n = colBase + wc * 64 + j * 16 + l15;
                int bb = m >> 10, s = m & 1023, hh = n >> 6, dh = n & 63;
                size_t hb = ((size_t)(bb * 16 + hh)) << 16;
                unsigned short v = rne_bf16(acc[i][j][r]);
                if (z == 0) {
                    O[hb + s * 64 + dh] = v;                 // Q row-major/head
                } else if (z == 1) {                         // K B-frag tiled
                    O[hb + (size_t)((s >> 4) * 2 + (dh >> 5)) * 512 +
                      ((dh >> 3) & 3) * 128 + (s & 15) * 8 + (dh & 7)] = v;
                } else {                                     // V^T B-frag tiled
                    O[hb + (size_t)((dh >> 4) * 32 + (s >> 5)) * 512 +
                      ((s >> 3) & 3) * 128 + (dh & 15) * 8 + (s & 7)] = v;
                }
            }
}

// ---------------------------------------------------------------------------
// Output projection, single pass: C = WS * Wo^T, fp32 out. 128x64 tile,
// BK=32, r5 body, grid (16,32) = 512 blocks = 2/CU.
// ---------------------------------------------------------------------------
__global__ __launch_bounds__(256)
void gemm_out1(const unsigned short* __restrict__ A,
               const unsigned short* __restrict__ Bh,
               float* __restrict__ Cf) {
    __shared__ unsigned short AS[128 * 32];
    __shared__ unsigned short BhS[64 * 32];

    const int t = threadIdx.x, lane = t & 63, w = t >> 6;
    const int quad = lane >> 4, l15 = lane & 15;
    const int wr = w & 1, wc = w >> 1;
    const int rowBase = blockIdx.y * 128, colBase = blockIdx.x * 64;

    const unsigned short* gA[2];
    unsigned short* lA[2];
    #pragma unroll
    for (int e = 0; e < 2; e++) {
        int row = w * 32 + e * 16 + (lane >> 2);
        int cg = (lane & 3) ^ ((row >> 1) & 3);
        gA[e] = A + (size_t)(rowBase + row) * 1024 + cg * 8;
        lA[e] = &AS[(w * 32 + e * 16) * 32];
    }
    const unsigned short* gBh;
    unsigned short* lBh;
    {
        int row = w * 16 + (lane >> 2);
        int cg = (lane & 3) ^ ((row >> 1) & 3);
        gBh = Bh + (size_t)(colBase + row) * 1024 + cg * 8;
        lBh = &BhS[(w * 16) * 32];
    }

    int aAd[4], bAd[2];
    #pragma unroll
    for (int i = 0; i < 4; i++) {
        int ra = wr * 64 + i * 16 + l15;
        aAd[i] = ra * 32 + (quad ^ ((ra >> 1) & 3)) * 8;
    }
    #pragma unroll
    for (int j = 0; j < 2; j++) {
        int rb = wc * 32 + j * 16 + l15;
        bAd[j] = rb * 32 + (quad ^ ((rb >> 1) & 3)) * 8;
    }

    f32x4 acc[4][2] = {};

    for (int kt = 0; kt < 32; kt++) {
        if (kt) __syncthreads();
        const int ko = kt * 32;
        glds16(gA[0] + ko, lA[0]);
        glds16(gA[1] + ko, lA[1]);
        glds16(gBh + ko, lBh);
        __syncthreads();

        bf16x8 af[4], bhf[2];
        #pragma unroll
        for (int i = 0; i < 4; i++) af[i] = *(const bf16x8*)&AS[aAd[i]];
        #pragma unroll
        for (int j = 0; j < 2; j++) bhf[j] = *(const bf16x8*)&BhS[bAd[j]];
        #pragma unroll
        for (int j = 0; j < 2; j++)
            #pragma unroll
            for (int i = 0; i < 4; i++)
                acc[i][j] = MFMA16(af[i], bhf[j], acc[i][j]);
    }

    #pragma unroll
    for (int i = 0; i < 4; i++)
        #pragma unroll
        for (int j = 0; j < 2; j++)
            #pragma unroll
            for (int r = 0; r < 4; r++) {
                int m = rowBase + wr * 64 + i * 16 + quad * 4 + r;
                int n = colBase + wc * 32 + j * 16 + l15;
                Cf[(size_t)m * 1024 + n] = acc[i][j][r];
            }
}

// ---------------------------------------------------------------------------
// Flash attention, barrier-free K-loop: K/V fragments loaded straight from
// frag-tiled global planes (coalesced 1 KB per load, L2-resident). No-max
// softmax (scores bounded). Wave owns 32 q-rows; block = 128 q-rows.
// P round-trip through per-wave LDS with additive chunk swizzle.
// ---------------------------------------------------------------------------
__global__ __launch_bounds__(256)
void attn_flat(const unsigned short* __restrict__ Qp,
               const unsigned short* __restrict__ Kf,
               const unsigned short* __restrict__ Vf,
               const int* __restrict__ mask, const float* __restrict__ gamma,
               unsigned short* __restrict__ WSr) {
    __shared__ int maskS[1024];
    __shared__ unsigned short Ph[4][32 * 72];

    const int t = threadIdx.x, lane = t & 63, w = t >> 6;
    const int quad = lane >> 4, l15 = lane & 15;
    const int q0 = blockIdx.x * 128, h = blockIdx.y, b = blockIdx.z;
    const size_t hb = ((size_t)(b * 16 + h)) << 16;

    ((int4*)maskS)[t] = ((const int4*)(mask + b * 1024))[t];

    bf16x8 qf[2][2];
    #pragma unroll
    for (int mi = 0; mi < 2; mi++) {
        size_t qb = hb + (size_t)(q0 + w * 32 + mi * 16 + l15) * 64 + quad * 8;
        qf[mi][0] = *(const bf16x8*)&Qp[qb];
        qf[mi][1] = *(const bf16x8*)&Qp[qb + 32];
    }

    f32x4 o[2][4] = {};
    float lsum[2][4] = {{0.f, 0.f, 0.f, 0.f}, {0.f, 0.f, 0.f, 0.f}};
    unsigned short* P = Ph[w];

    __syncthreads();  // maskS ready (only block-wide sync in the kernel)

    for (int jt = 0; jt < 16; jt++) {
        const int j0 = jt * 64;
        if (maskS[j0]) break;  // monotonic mask
        const bool partial = maskS[j0 + 63] != 0;

        // K fragments (coalesced 1 KB each)
        bf16x8 kv[4][2];
        #pragma unroll
        for (int nj = 0; nj < 4; nj++)
            #pragma unroll
            for (int kk = 0; kk < 2; kk++)
                kv[nj][kk] = *(const bf16x8*)&Kf[hb + (size_t)((jt * 4 + nj) * 2 + kk) * 512 + lane * 8];

        f32x4 s4[2][4] = {};
        #pragma unroll
        for (int nj = 0; nj < 4; nj++)
            #pragma unroll
            for (int kk = 0; kk < 2; kk++)
                #pragma unroll
                for (int mi = 0; mi < 2; mi++)
                    s4[mi][nj] = MFMA16(qf[mi][kk], kv[nj][kk], s4[mi][nj]);

        // V fragments issued early (overlap with exp below)
        bf16x8 vv[4][2];
        #pragma unroll
        for (int dt = 0; dt < 4; dt++)
            #pragma unroll
            for (int ks = 0; ks < 2; ks++)
                vv[dt][ks] = *(const bf16x8*)&Vf[hb + (size_t)(dt * 32 + jt * 2 + ks) * 512 + lane * 8];

        // p = exp(s/8) (no max needed), write swizzled bf16 P
        #pragma unroll
        for (int mi = 0; mi < 2; mi++)
            #pragma unroll
            for (int nj = 0; nj < 4; nj++) {
                int mk = partial ? maskS[j0 + nj * 16 + l15] : 0;
                #pragma unroll
                for (int r = 0; r < 4; r++) {
                    float p = mk ? 0.f : __expf(s4[mi][nj][r] * 0.125f);
                    lsum[mi][r] += p;
                    int rowW = mi * 16 + quad * 4 + r;
                    int slot = ((nj * 2 + (l15 >> 3)) - 2 * rowW) & 7;
                    P[rowW * 72 + slot * 8 + (l15 & 7)] = rne_bf16(p);
                }
            }

        // P fragments (uniform bank groups), then O += P V
        bf16x8 pf[2][2];
        #pragma unroll
        for (int mi = 0; mi < 2; mi++) {
            int rowR = mi * 16 + l15;
            int sl0 = (quad - 2 * rowR) & 7;
            pf[mi][0] = *(const bf16x8*)&P[rowR * 72 + sl0 * 8];
            pf[mi][1] = *(const bf16x8*)&P[rowR * 72 + ((sl0 + 4) & 7) * 8];
        }
        #pragma unroll
        for (int dt = 0; dt < 4; dt++)
            #pragma unroll
            for (int ks = 0; ks < 2; ks++)
                #pragma unroll
                for (int mi = 0; mi < 2; mi++)
                    o[mi][dt] = MFMA16(pf[mi][ks], vv[dt][ks], o[mi][dt]);
    }

    #pragma unroll
    for (int mi = 0; mi < 2; mi++)
        #pragma unroll
        for (int r = 0; r < 4; r++) {
            lsum[mi][r] += __shfl_xor(lsum[mi][r], 1);
            lsum[mi][r] += __shfl_xor(lsum[mi][r], 2);
            lsum[mi][r] += __shfl_xor(lsum[mi][r], 4);
            lsum[mi][r] += __shfl_xor(lsum[mi][r], 8);
        }

    // epilogue: WS row-major [b*1024+s][h*64+dh], gamma/l fused
    const float g = gamma[h];
    #pragma unroll
    for (int mi = 0; mi < 2; mi++)
        #pragma unroll
        for (int r = 0; r < 4; r++) {
            int qrow = q0 + w * 32 + mi * 16 + quad * 4 + r;
            float sc = g / lsum[mi][r];
            size_t base = ((size_t)b * 1024 + qrow) * 1024 + h * 64;
            #pragma unroll
            for (int dt = 0; dt < 4; dt++)
                WSr[base + dt * 16 + l15] = rne_bf16(o[mi][dt][r] * sc);
        }
}

// ---------------------------------------------------------------------------
extern "C" void kernel_launch(void* const* d_in, const int* in_sizes, int n_in,
                              void* d_out, int out_size, void* d_ws, size_t ws_size,
                              hipStream_t stream) {
    const float* query = (const float*)d_in[0];
    const float* key   = (const float*)d_in[1];
    const float* value = (const float*)d_in[2];
    const int*   mask  = (const int*)d_in[3];
    const float* Wq    = (const float*)d_in[4];
    const float* Wk    = (const float*)d_in[5];
    const float* Wv    = (const float*)d_in[6];
    const float* Wo    = (const float*)d_in[7];
    const float* gamma = (const float*)d_in[8];
    float* out = (float*)d_out;

    unsigned short* u = (unsigned short*)d_ws;
    // 56 MB layout (28M ushorts):
    unsigned short* Xb  = u;            // Xq,Xk,Xv bf16 row-major (3 x XPL)
    unsigned short* QKV = u + 3 * XPL;  // Qp, Kf, Vf head planes (3 x XPL)
    unsigned short* Wb  = u + 6 * XPL;  // Wq,Wk,Wv,Wo bf16 row-major (4 x WPL)
    unsigned short* WSr = Xb;           // alias: Xq dead after proj
    unsigned short* Qp = QKV, *Kfp = QKV + XPL, *Vfp = QKV + 2 * XPL;
    unsigned short* Wob = Wb + 3 * WPL;

    convert_all<<<16384, 256, 0, stream>>>(Wq, Wk, Wv, Wo, query, key, value, Wb, Xb);

    gemm_proj<<<dim3(8, 32, 3), 256, 0, stream>>>(Xb, Wb, QKV);

    attn_flat<<<dim3(8, 16, 4), 256, 0, stream>>>(Qp, Kfp, Vfp, mask, gamma, WSr);

    gemm_out1<<<dim3(16, 32), 256, 0, stream>>>(WSr, Wob, out);
}